// Round 1
// baseline (126.305 us; speedup 1.0000x reference)
//
#include <hip/hip_runtime.h>
#include <hip/hip_bf16.h>

typedef __attribute__((ext_vector_type(8))) short short8;
typedef __attribute__((ext_vector_type(4))) float f32x4;

#define DIMD 128
#define NSPLIT 8

// ---------------- Kernel 1: normalize rows of [z_i; z_j] -> bf16, zero out ----
__global__ __launch_bounds__(256) void nrm_kernel(const float* __restrict__ zi,
                                                  const float* __restrict__ zj,
                                                  __hip_bfloat16* __restrict__ zn,
                                                  float* __restrict__ out, int B) {
  if (blockIdx.x == 0 && threadIdx.x == 0) out[0] = 0.0f;
  int wave = threadIdx.x >> 6, lane = threadIdx.x & 63;
  int N = 2 * B;
  int row = blockIdx.x * 4 + wave;
  if (row >= N) return;
  const float* src = (row < B) ? (zi + (size_t)row * DIMD)
                               : (zj + (size_t)(row - B) * DIMD);
  float2 v = *(const float2*)(src + lane * 2);
  float ss = v.x * v.x + v.y * v.y;
  #pragma unroll
  for (int off = 32; off; off >>= 1) ss += __shfl_xor(ss, off);
  float nrm = sqrtf(ss);
  float r = 1.0f / fmaxf(nrm, 1e-8f);
  __hip_bfloat16* dst = zn + (size_t)row * DIMD + lane * 2;
  dst[0] = __float2bfloat16(v.x * r);
  dst[1] = __float2bfloat16(v.y * r);
}

// ---------------- Kernel 2: fused zn*zn^T -> sum of exp per row (partial) ----
// grid: (N/64 row-stripes, NSPLIT column splits), block 256 (4 waves).
// Each wave owns 16 rows; loops over 16-col tiles of its split.
__global__ __launch_bounds__(256) void sim_kernel(const __hip_bfloat16* __restrict__ znb,
                                                  float* __restrict__ partial,
                                                  float* __restrict__ pos, int B) {
  const ushort* zn = (const ushort*)znb;
  const int N = 2 * B;
  const int wave = threadIdx.x >> 6, lane = threadIdx.x & 63;
  const int l15 = lane & 15, lh = lane >> 4;
  const int R16 = blockIdx.x * 64 + wave * 16;          // this wave's 16 rows
  const int colsPerSplit = N / NSPLIT;
  const int C0 = blockIdx.y * colsPerSplit;

  // A fragments for this wave's 16 rows, K=128 in 4 chunks of 32.
  // lane l, elems j: A[row = l&15][k = kc*32 + 8*(l>>4) + j]  (consistent
  // indexing for A and B makes any k-permutation cancel in A*A^T).
  const ushort* arow = zn + (size_t)(R16 + l15) * DIMD + lh * 8;
  short8 a0 = *(const short8*)(arow);
  short8 a1 = *(const short8*)(arow + 32);
  short8 a2 = *(const short8*)(arow + 64);
  short8 a3 = *(const short8*)(arow + 96);

  float rs[4] = {0.f, 0.f, 0.f, 0.f};
  const int diagT = R16 >> 4;
  const int partT = ((R16 + B) & (N - 1)) >> 4;
  const float kEXP = 2.8853900817779268f;  // 2 (1/temperature) * log2(e)

  for (int ct = 0; ct < colsPerSplit / 16; ++ct) {
    const int C = C0 + ct * 16;
    const ushort* brow = zn + (size_t)(C + l15) * DIMD + lh * 8;
    short8 b0 = *(const short8*)(brow);
    short8 b1 = *(const short8*)(brow + 32);
    short8 b2 = *(const short8*)(brow + 64);
    short8 b3 = *(const short8*)(brow + 96);
    f32x4 acc = {0.f, 0.f, 0.f, 0.f};
    acc = __builtin_amdgcn_mfma_f32_16x16x32_bf16(a0, b0, acc, 0, 0, 0);
    acc = __builtin_amdgcn_mfma_f32_16x16x32_bf16(a1, b1, acc, 0, 0, 0);
    acc = __builtin_amdgcn_mfma_f32_16x16x32_bf16(a2, b2, acc, 0, 0, 0);
    acc = __builtin_amdgcn_mfma_f32_16x16x32_bf16(a3, b3, acc, 0, 0, 0);

    const int gt = C >> 4;
    if (gt == diagT || gt == partT) {
      // slow path: this tile may contain self-diagonal and/or positive pair
      #pragma unroll
      for (int r = 0; r < 4; ++r) {
        int i = R16 + lh * 4 + r;           // C/D: row=(lane>>4)*4+reg
        int jg = C + l15;                   //       col=lane&15
        float s = acc[r] * 2.0f;            // sim = dot / 0.5
        if (jg == ((i + B) & (N - 1))) pos[i] = s;
        float e = __builtin_amdgcn_exp2f(s * 1.4426950408889634f);
        if (jg != i) rs[r] += e;
      }
    } else {
      #pragma unroll
      for (int r = 0; r < 4; ++r)
        rs[r] += __builtin_amdgcn_exp2f(acc[r] * kEXP);
    }
  }

  // reduce each row's partial across the 16 lanes sharing (lane>>4)
  #pragma unroll
  for (int r = 0; r < 4; ++r) {
    #pragma unroll
    for (int off = 1; off < 16; off <<= 1) rs[r] += __shfl_xor(rs[r], off);
  }
  if (l15 == 0) {
    #pragma unroll
    for (int r = 0; r < 4; ++r)
      partial[(size_t)(R16 + lh * 4 + r) * NSPLIT + blockIdx.y] = rs[r];
  }
}

// ---------------- Kernel 3: row_loss = log(sum) - pos; mean over rows -------
__global__ __launch_bounds__(256) void fin_kernel(const float* __restrict__ partial,
                                                  const float* __restrict__ pos,
                                                  float* __restrict__ out, int N) {
  int i = blockIdx.x * 256 + threadIdx.x;
  float li = 0.0f;
  if (i < N) {
    float s = 0.0f;
    #pragma unroll
    for (int q = 0; q < NSPLIT; ++q) s += partial[(size_t)i * NSPLIT + q];
    li = __builtin_amdgcn_logf(s) * 0.6931471805599453f - pos[i];
  }
  #pragma unroll
  for (int off = 32; off; off >>= 1) li += __shfl_xor(li, off);
  __shared__ float red[4];
  int wave = threadIdx.x >> 6, lane = threadIdx.x & 63;
  if (lane == 0) red[wave] = li;
  __syncthreads();
  if (threadIdx.x == 0) {
    float bs = red[0] + red[1] + red[2] + red[3];
    atomicAdd(out, bs / (float)N);
  }
}

extern "C" void kernel_launch(void* const* d_in, const int* in_sizes, int n_in,
                              void* d_out, int out_size, void* d_ws, size_t ws_size,
                              hipStream_t stream) {
  const float* zi = (const float*)d_in[0];
  const float* zj = (const float*)d_in[1];
  const int B = in_sizes[0] / DIMD;   // 4096
  const int N = 2 * B;                // 8192
  float* out = (float*)d_out;

  char* ws = (char*)d_ws;
  __hip_bfloat16* zn = (__hip_bfloat16*)ws;                       // N*D*2 bytes
  float* partial = (float*)(ws + (size_t)N * DIMD * 2);           // N*NSPLIT*4
  float* pos = (float*)(ws + (size_t)N * DIMD * 2 + (size_t)N * NSPLIT * 4);

  nrm_kernel<<<N / 4, 256, 0, stream>>>(zi, zj, zn, out, B);
  dim3 g2(N / 64, NSPLIT);
  sim_kernel<<<g2, 256, 0, stream>>>(zn, partial, pos, B);
  fin_kernel<<<N / 256, 256, 0, stream>>>(partial, pos, out, N);
}

// Round 2
// 52.670 us; speedup vs baseline: 2.3980x; 2.3980x over previous
//
#include <hip/hip_runtime.h>
#include <hip/hip_bf16.h>

typedef __attribute__((ext_vector_type(8))) short short8;
typedef __attribute__((ext_vector_type(4))) float f32x4;

#define DIMD 128
#define NSPLIT 32
#define WR 64              // rows per wave
#define ROWS_PER_BLOCK 256 // 4 waves * WR

// ---------------- Kernel 1: normalize rows of [z_i; z_j] -> bf16, zero out ----
__global__ __launch_bounds__(256) void nrm_kernel(const float* __restrict__ zi,
                                                  const float* __restrict__ zj,
                                                  __hip_bfloat16* __restrict__ zn,
                                                  float* __restrict__ out, int B) {
  if (blockIdx.x == 0 && threadIdx.x == 0) out[0] = 0.0f;
  int wave = threadIdx.x >> 6, lane = threadIdx.x & 63;
  int N = 2 * B;
  int row = blockIdx.x * 4 + wave;
  if (row >= N) return;
  const float* src = (row < B) ? (zi + (size_t)row * DIMD)
                               : (zj + (size_t)(row - B) * DIMD);
  float2 v = *(const float2*)(src + lane * 2);
  float ss = v.x * v.x + v.y * v.y;
  #pragma unroll
  for (int off = 32; off; off >>= 1) ss += __shfl_xor(ss, off);
  float nrm = sqrtf(ss);
  float r = 1.0f / fmaxf(nrm, 1e-8f);
  __hip_bfloat16* dst = zn + (size_t)row * DIMD + lane * 2;
  dst[0] = __float2bfloat16(v.x * r);
  dst[1] = __float2bfloat16(v.y * r);
}

// ---------------- Kernel 2: fused zn*zn^T -> sum of exp per row (partial) ----
// grid: (N/256 row-stripes, NSPLIT column splits), block 256 (4 waves).
// Each wave owns 64 rows (4 row-groups of 16, A in registers);
// loops over 16-col B tiles of its split with register double-buffering.

#define TILE_LOAD(bb, CC)                                                  \
  {                                                                        \
    const ushort* br_ = zn + (size_t)((CC) + l15) * DIMD + lh * 8;         \
    _Pragma("unroll")                                                      \
    for (int kc = 0; kc < 4; ++kc) bb[kc] = *(const short8*)(br_ + kc * 32); \
  }

#define TILE_COMPUTE(bb, CC)                                               \
  {                                                                        \
    const int gt_ = (CC) >> 4;                                             \
    _Pragma("unroll")                                                      \
    for (int rg = 0; rg < 4; ++rg) {                                       \
      f32x4 acc = {0.f, 0.f, 0.f, 0.f};                                    \
      acc = __builtin_amdgcn_mfma_f32_16x16x32_bf16(a[rg][0], bb[0], acc, 0, 0, 0); \
      acc = __builtin_amdgcn_mfma_f32_16x16x32_bf16(a[rg][1], bb[1], acc, 0, 0, 0); \
      acc = __builtin_amdgcn_mfma_f32_16x16x32_bf16(a[rg][2], bb[2], acc, 0, 0, 0); \
      acc = __builtin_amdgcn_mfma_f32_16x16x32_bf16(a[rg][3], bb[3], acc, 0, 0, 0); \
      if (gt_ == diagT[rg] || gt_ == partT[rg]) {                          \
        _Pragma("unroll")                                                  \
        for (int r = 0; r < 4; ++r) {                                      \
          int i_ = R + rg * 16 + lh * 4 + r;                               \
          int jg_ = (CC) + l15;                                            \
          float s_ = acc[r] * 2.0f;                                        \
          if (jg_ == ((i_ + B) & (N - 1))) pos[i_] = s_;                   \
          if (jg_ != i_)                                                   \
            rs[rg][r] += __builtin_amdgcn_exp2f(s_ * 1.4426950408889634f); \
        }                                                                  \
      } else {                                                             \
        _Pragma("unroll")                                                  \
        for (int r = 0; r < 4; ++r)                                        \
          rs[rg][r] += __builtin_amdgcn_exp2f(acc[r] * kEXP);              \
      }                                                                    \
    }                                                                      \
  }

__global__ __launch_bounds__(256) void sim_kernel(const __hip_bfloat16* __restrict__ znb,
                                                  float* __restrict__ partial,
                                                  float* __restrict__ pos, int B) {
  const ushort* zn = (const ushort*)znb;
  const int N = 2 * B;
  const int wave = threadIdx.x >> 6, lane = threadIdx.x & 63;
  const int l15 = lane & 15, lh = lane >> 4;
  const int R = blockIdx.x * ROWS_PER_BLOCK + wave * WR;  // this wave's 64 rows
  const int colsPerSplit = N / NSPLIT;
  const int C0 = blockIdx.y * colsPerSplit;
  const float kEXP = 2.8853900817779268f;  // 2 (1/temperature) * log2(e)

  // A fragments: 4 row-groups x 4 k-chunks (held in registers for the
  // whole kernel). lane l, elems j: A[row = l&15][k = kc*32 + 8*(l>>4) + j].
  short8 a[4][4];
  #pragma unroll
  for (int rg = 0; rg < 4; ++rg) {
    const ushort* ar = zn + (size_t)(R + rg * 16 + l15) * DIMD + lh * 8;
    #pragma unroll
    for (int kc = 0; kc < 4; ++kc) a[rg][kc] = *(const short8*)(ar + kc * 32);
  }

  float rs[4][4];
  #pragma unroll
  for (int rg = 0; rg < 4; ++rg)
    #pragma unroll
    for (int r = 0; r < 4; ++r) rs[rg][r] = 0.0f;

  int diagT[4], partT[4];
  #pragma unroll
  for (int rg = 0; rg < 4; ++rg) {
    diagT[rg] = (R + rg * 16) >> 4;
    partT[rg] = ((R + rg * 16 + B) & (N - 1)) >> 4;
  }

  const int nt = colsPerSplit / 16;  // 16 tiles (even)
  short8 b0[4], b1[4];
  TILE_LOAD(b0, C0);
  for (int ct = 0; ct < nt; ct += 2) {
    const int C = C0 + ct * 16;
    TILE_LOAD(b1, C + 16);          // prefetch odd tile
    TILE_COMPUTE(b0, C);
    if (ct + 2 < nt) TILE_LOAD(b0, C + 32);  // prefetch next even tile
    TILE_COMPUTE(b1, C + 16);
  }

  // reduce each row's partial across the 16 lanes sharing (lane>>4)
  #pragma unroll
  for (int rg = 0; rg < 4; ++rg) {
    #pragma unroll
    for (int r = 0; r < 4; ++r) {
      #pragma unroll
      for (int off = 1; off < 16; off <<= 1)
        rs[rg][r] += __shfl_xor(rs[rg][r], off);
    }
  }
  if (l15 == 0) {
    #pragma unroll
    for (int rg = 0; rg < 4; ++rg)
      #pragma unroll
      for (int r = 0; r < 4; ++r)
        partial[(size_t)(R + rg * 16 + lh * 4 + r) * NSPLIT + blockIdx.y] = rs[rg][r];
  }
}

// ---------------- Kernel 3: row_loss = log(sum) - pos; mean over rows -------
__global__ __launch_bounds__(256) void fin_kernel(const float* __restrict__ partial,
                                                  const float* __restrict__ pos,
                                                  float* __restrict__ out, int N) {
  int i = blockIdx.x * 256 + threadIdx.x;
  float li = 0.0f;
  if (i < N) {
    float s = 0.0f;
    #pragma unroll
    for (int q = 0; q < NSPLIT; ++q) s += partial[(size_t)i * NSPLIT + q];
    li = __builtin_amdgcn_logf(s) * 0.6931471805599453f - pos[i];
  }
  #pragma unroll
  for (int off = 32; off; off >>= 1) li += __shfl_xor(li, off);
  __shared__ float red[4];
  int wave = threadIdx.x >> 6, lane = threadIdx.x & 63;
  if (lane == 0) red[wave] = li;
  __syncthreads();
  if (threadIdx.x == 0) {
    float bs = red[0] + red[1] + red[2] + red[3];
    atomicAdd(out, bs / (float)N);
  }
}

extern "C" void kernel_launch(void* const* d_in, const int* in_sizes, int n_in,
                              void* d_out, int out_size, void* d_ws, size_t ws_size,
                              hipStream_t stream) {
  const float* zi = (const float*)d_in[0];
  const float* zj = (const float*)d_in[1];
  const int B = in_sizes[0] / DIMD;   // 4096
  const int N = 2 * B;                // 8192
  float* out = (float*)d_out;

  char* ws = (char*)d_ws;
  __hip_bfloat16* zn = (__hip_bfloat16*)ws;                       // N*D*2 bytes
  float* partial = (float*)(ws + (size_t)N * DIMD * 2);           // N*NSPLIT*4
  float* pos = (float*)(ws + (size_t)N * DIMD * 2 + (size_t)N * NSPLIT * 4);

  nrm_kernel<<<N / 4, 256, 0, stream>>>(zi, zj, zn, out, B);
  dim3 g2(N / ROWS_PER_BLOCK, NSPLIT);
  sim_kernel<<<g2, 256, 0, stream>>>(zn, partial, pos, B);
  fin_kernel<<<N / 256, 256, 0, stream>>>(partial, pos, out, N);
}

// Round 3
// 45.219 us; speedup vs baseline: 2.7932x; 1.1648x over previous
//
#include <hip/hip_runtime.h>
#include <hip/hip_bf16.h>

typedef __attribute__((ext_vector_type(8))) short short8;
typedef __attribute__((ext_vector_type(4))) float f32x4;

#define DIMD 128
#define NSPLIT 32
#define WR 64               // rows per wave
#define ROWS_PER_BLOCK 256  // 4 waves * WR
#define CPS 64              // cols per LDS stage

// scale = sqrt(2 * log2(e)) so that acc = (c*zn_i)·(c*zn_j) = 2*log2(e)*cos
// -> exp2(acc) = e^(cos/T) directly, and logit s = acc * ln2.
#define ZSCALE 1.69864363f
#define LN2 0.6931471805599453f

// ---------------- Kernel 1: normalize rows of [z_i; z_j] -> scaled bf16 ------
__global__ __launch_bounds__(256) void nrm_kernel(const float* __restrict__ zi,
                                                  const float* __restrict__ zj,
                                                  __hip_bfloat16* __restrict__ zn,
                                                  float* __restrict__ out, int B) {
  if (blockIdx.x == 0 && threadIdx.x == 0) out[0] = 0.0f;
  int wave = threadIdx.x >> 6, lane = threadIdx.x & 63;
  int N = 2 * B;
  int row = blockIdx.x * 4 + wave;
  if (row >= N) return;
  const float* src = (row < B) ? (zi + (size_t)row * DIMD)
                               : (zj + (size_t)(row - B) * DIMD);
  float2 v = *(const float2*)(src + lane * 2);
  float ss = v.x * v.x + v.y * v.y;
  #pragma unroll
  for (int off = 32; off; off >>= 1) ss += __shfl_xor(ss, off);
  float nrm = sqrtf(ss);
  float r = ZSCALE / fmaxf(nrm, 1e-8f);
  __hip_bfloat16* dst = zn + (size_t)row * DIMD + lane * 2;
  dst[0] = __float2bfloat16(v.x * r);
  dst[1] = __float2bfloat16(v.y * r);
}

// ---------------- Kernel 2: fused zn*zn^T -> sum of exp per row (partial) ----
// grid: (N/256 row-stripes, NSPLIT column splits), block 256 (4 waves).
// Wave owns 64 rows (A in registers). Block stages 64-col B tiles in LDS
// (double-buffered, XOR-swizzled), shared by all 4 waves. Reg-staged
// issue-early / write-late pipeline, one barrier per stage.

// staging: thread tid handles, per round r (0..3): col = r*16 + (tid>>4),
// k-chunk kb = tid&15 (16B each). LDS slot for (col,kb) is kb^(col&7).
#define STAGE_LOAD(GG, CC)                                                  \
  {                                                                         \
    _Pragma("unroll")                                                       \
    for (int r_ = 0; r_ < 4; ++r_) {                                        \
      int col_ = r_ * 16 + scol;                                            \
      GG[r_] = *(const short8*)(zn + (size_t)((CC) + col_) * DIMD + skb * 8); \
    }                                                                       \
  }

#define STAGE_WRITE(BUF, GG)                                                \
  {                                                                         \
    _Pragma("unroll")                                                       \
    for (int r_ = 0; r_ < 4; ++r_) {                                        \
      int col_ = r_ * 16 + scol;                                            \
      *(short8*)(&lds[BUF][col_ * DIMD + ((skb ^ (col_ & 7)) * 8)]) = GG[r_]; \
    }                                                                       \
  }

#define COMPUTE(BUF, CC)                                                    \
  {                                                                         \
    _Pragma("unroll")                                                       \
    for (int sub = 0; sub < 4; ++sub) {                                     \
      const int cw_ = sub * 16 + l15;                                       \
      const ushort* lp_ = &lds[BUF][cw_ * DIMD];                            \
      short8 bb[4];                                                         \
      _Pragma("unroll")                                                     \
      for (int kc = 0; kc < 4; ++kc)                                        \
        bb[kc] = *(const short8*)(lp_ + (((kc * 4 + lh) ^ (cw_ & 7)) * 8)); \
      const int gt_ = ((CC) + sub * 16) >> 4;                               \
      _Pragma("unroll")                                                     \
      for (int rg = 0; rg < 4; ++rg) {                                      \
        f32x4 acc = {0.f, 0.f, 0.f, 0.f};                                   \
        acc = __builtin_amdgcn_mfma_f32_16x16x32_bf16(a[rg][0], bb[0], acc, 0, 0, 0); \
        acc = __builtin_amdgcn_mfma_f32_16x16x32_bf16(a[rg][1], bb[1], acc, 0, 0, 0); \
        acc = __builtin_amdgcn_mfma_f32_16x16x32_bf16(a[rg][2], bb[2], acc, 0, 0, 0); \
        acc = __builtin_amdgcn_mfma_f32_16x16x32_bf16(a[rg][3], bb[3], acc, 0, 0, 0); \
        if (gt_ == diagT[rg] || gt_ == partT[rg]) {                         \
          _Pragma("unroll")                                                 \
          for (int r = 0; r < 4; ++r) {                                     \
            int i_ = R + rg * 16 + lh * 4 + r;                              \
            int jg_ = (CC) + sub * 16 + l15;                                \
            if (jg_ == ((i_ + B) & (N - 1))) pos[i_] = acc[r] * LN2;        \
            if (jg_ != i_) rs[rg][r] += __builtin_amdgcn_exp2f(acc[r]);     \
          }                                                                 \
        } else {                                                            \
          _Pragma("unroll")                                                 \
          for (int r = 0; r < 4; ++r)                                       \
            rs[rg][r] += __builtin_amdgcn_exp2f(acc[r]);                    \
        }                                                                   \
      }                                                                     \
    }                                                                       \
  }

__global__ __launch_bounds__(256) void sim_kernel(const __hip_bfloat16* __restrict__ znb,
                                                  float* __restrict__ partial,
                                                  float* __restrict__ pos, int B) {
  const ushort* zn = (const ushort*)znb;
  const int N = 2 * B;
  const int tid = threadIdx.x;
  const int wave = tid >> 6, lane = tid & 63;
  const int l15 = lane & 15, lh = lane >> 4;
  const int scol = tid >> 4, skb = tid & 15;
  const int R = blockIdx.x * ROWS_PER_BLOCK + wave * WR;
  const int colsPerSplit = N / NSPLIT;      // 256
  const int C0 = blockIdx.y * colsPerSplit;
  const int NST = colsPerSplit / CPS;       // 4

  __shared__ ushort lds[2][CPS * DIMD];     // 2 x 16 KB

  // A fragments: 4 row-groups x 4 k-chunks, resident all kernel.
  // lane l, elems j: A[row = l&15][k = kc*32 + 8*(l>>4) + j]
  short8 a[4][4];
  #pragma unroll
  for (int rg = 0; rg < 4; ++rg) {
    const ushort* ar = zn + (size_t)(R + rg * 16 + l15) * DIMD + lh * 8;
    #pragma unroll
    for (int kc = 0; kc < 4; ++kc) a[rg][kc] = *(const short8*)(ar + kc * 32);
  }

  float rs[4][4];
  #pragma unroll
  for (int rg = 0; rg < 4; ++rg)
    #pragma unroll
    for (int r = 0; r < 4; ++r) rs[rg][r] = 0.0f;

  int diagT[4], partT[4];
  #pragma unroll
  for (int rg = 0; rg < 4; ++rg) {
    diagT[rg] = (R + rg * 16) >> 4;
    partT[rg] = ((R + rg * 16 + B) & (N - 1)) >> 4;
  }

  short8 g[4];
  STAGE_LOAD(g, C0);
  STAGE_WRITE(0, g);
  __syncthreads();

  for (int st = 0; st < NST; ++st) {
    const int C = C0 + st * CPS;
    if (st + 1 < NST) STAGE_LOAD(g, C + CPS);   // issue early (hides under MFMA)
    COMPUTE(st & 1, C);
    if (st + 1 < NST) STAGE_WRITE((st + 1) & 1, g);  // write late
    __syncthreads();
  }

  // reduce each row's partial across the 16 lanes sharing (lane>>4)
  #pragma unroll
  for (int rg = 0; rg < 4; ++rg) {
    #pragma unroll
    for (int r = 0; r < 4; ++r) {
      #pragma unroll
      for (int off = 1; off < 16; off <<= 1)
        rs[rg][r] += __shfl_xor(rs[rg][r], off);
    }
  }
  if (l15 == 0) {
    #pragma unroll
    for (int rg = 0; rg < 4; ++rg)
      #pragma unroll
      for (int r = 0; r < 4; ++r)
        partial[(size_t)(R + rg * 16 + lh * 4 + r) * NSPLIT + blockIdx.y] = rs[rg][r];
  }
}

// ---------------- Kernel 3: row_loss = log(sum) - pos; mean over rows -------
__global__ __launch_bounds__(256) void fin_kernel(const float* __restrict__ partial,
                                                  const float* __restrict__ pos,
                                                  float* __restrict__ out, int N) {
  int i = blockIdx.x * 256 + threadIdx.x;
  float li = 0.0f;
  if (i < N) {
    float s = 0.0f;
    #pragma unroll
    for (int q = 0; q < NSPLIT; ++q) s += partial[(size_t)i * NSPLIT + q];
    li = __builtin_amdgcn_logf(s) * LN2 - pos[i];
  }
  #pragma unroll
  for (int off = 32; off; off >>= 1) li += __shfl_xor(li, off);
  __shared__ float red[4];
  int wave = threadIdx.x >> 6, lane = threadIdx.x & 63;
  if (lane == 0) red[wave] = li;
  __syncthreads();
  if (threadIdx.x == 0) {
    float bs = red[0] + red[1] + red[2] + red[3];
    atomicAdd(out, bs / (float)N);
  }
}

extern "C" void kernel_launch(void* const* d_in, const int* in_sizes, int n_in,
                              void* d_out, int out_size, void* d_ws, size_t ws_size,
                              hipStream_t stream) {
  const float* zi = (const float*)d_in[0];
  const float* zj = (const float*)d_in[1];
  const int B = in_sizes[0] / DIMD;   // 4096
  const int N = 2 * B;                // 8192
  float* out = (float*)d_out;

  char* ws = (char*)d_ws;
  __hip_bfloat16* zn = (__hip_bfloat16*)ws;                       // N*D*2 bytes
  float* partial = (float*)(ws + (size_t)N * DIMD * 2);           // N*NSPLIT*4
  float* pos = (float*)(ws + (size_t)N * DIMD * 2 + (size_t)N * NSPLIT * 4);

  nrm_kernel<<<N / 4, 256, 0, stream>>>(zi, zj, zn, out, B);
  dim3 g2(N / ROWS_PER_BLOCK, NSPLIT);
  sim_kernel<<<g2, 256, 0, stream>>>(zn, partial, pos, B);
  fin_kernel<<<N / 256, 256, 0, stream>>>(partial, pos, out, N);
}